// Round 2
// baseline (750.142 us; speedup 1.0000x reference)
//
#include <hip/hip_runtime.h>
#include <hip/hip_bf16.h>

// S=64, C=27
// DOTLEN = C*S*5 = 8640 (2160 float4) ; per-node state = S*5 = 320 ; comb = 640 ; hidden = 64
#define DOTLEN 8640
#define DOT4   2160

__device__ __forceinline__ float wave_reduce_sum(float v) {
    v += __shfl_xor(v, 32, 64);
    v += __shfl_xor(v, 16, 64);
    v += __shfl_xor(v, 8, 64);
    v += __shfl_xor(v, 4, 64);
    v += __shfl_xor(v, 2, 64);
    v += __shfl_xor(v, 1, 64);
    return v;
}

__device__ __forceinline__ float fma4(float4 w, float4 x, float acc) {
    acc = fmaf(w.x, x.x, acc);
    acc = fmaf(w.y, x.y, acc);
    acc = fmaf(w.z, x.z, acc);
    acc = fmaf(w.w, x.w, acc);
    return acc;
}

// Wave-distributed dot of one 8640-float row against x. 4 independent acc
// chains, 8 loads issued per unrolled step -> high memory-level parallelism.
__device__ __forceinline__ float row_dot(const float4* __restrict__ Wr,
                                         const float4* __restrict__ xr,
                                         int lane) {
    float a0 = 0.f, a1 = 0.f, a2 = 0.f, a3 = 0.f;
    #pragma unroll 2
    for (int base = 0; base < 2048; base += 256) {
        float4 w0 = Wr[base + lane];
        float4 w1 = Wr[base + 64 + lane];
        float4 w2 = Wr[base + 128 + lane];
        float4 w3 = Wr[base + 192 + lane];
        float4 x0 = xr[base + lane];
        float4 x1 = xr[base + 64 + lane];
        float4 x2 = xr[base + 128 + lane];
        float4 x3 = xr[base + 192 + lane];
        a0 = fma4(w0, x0, a0);
        a1 = fma4(w1, x1, a1);
        a2 = fma4(w2, x2, a2);
        a3 = fma4(w3, x3, a3);
    }
    // tail: indices 2048..2159 (112 float4)
    {
        float4 w = Wr[2048 + lane];
        float4 x = xr[2048 + lane];
        a0 = fma4(w, x, a0);
    }
    if (lane < 48) {
        float4 w = Wr[2112 + lane];
        float4 x = xr[2112 + lane];
        a1 = fma4(w, x, a1);
    }
    return (a0 + a1) + (a2 + a3);
}

// Two-layer MLP tail: assumes comb[0:640] staged in LDS (caller), writes
// outp[i] = comb[i] + W2@relu(W1@comb + b1) + b2.  256 threads.
__device__ __forceinline__ void mlp_core(int tid,
                                         const float* __restrict__ W1,
                                         const float* __restrict__ b1,
                                         const float* __restrict__ W2,
                                         const float* __restrict__ b2,
                                         float* __restrict__ outp,
                                         float* comb, float* h) {
    __syncthreads();
    const int wv = tid >> 6, lane = tid & 63;
    for (int k = wv * 16; k < wv * 16 + 16; ++k) {
        float acc = 0.f;
        #pragma unroll
        for (int j = lane; j < 640; j += 64)
            acc = fmaf(W1[k * 640 + j], comb[j], acc);
        acc = wave_reduce_sum(acc);
        if (lane == 0) h[k] = fmaxf(acc + b1[k], 0.f);
    }
    __syncthreads();
    for (int i = tid; i < 320; i += 256) {
        const float4* __restrict__ w = reinterpret_cast<const float4*>(W2 + (size_t)i * 64);
        float acc = 0.f;
        #pragma unroll
        for (int j4 = 0; j4 < 16; ++j4) {
            float4 ww = w[j4];
            acc = fmaf(ww.x, h[4 * j4 + 0], acc);
            acc = fmaf(ww.y, h[4 * j4 + 1], acc);
            acc = fmaf(ww.z, h[4 * j4 + 2], acc);
            acc = fmaf(ww.w, h[4 * j4 + 3], acc);
        }
        outp[i] = comb[i] + acc + b2[i];
    }
}

// Kernel 1: agg1 = agg_W1 . leaf_flat + agg_b1 (8640 rows, 4 rows/block,
// 80 blocks per node). Last block of each node runs that node's update MLP.
__global__ void __launch_bounds__(256) k1_agg_mlp(
    const float* __restrict__ W,        // agg_W1 [27*320][8640]
    const float* __restrict__ x,        // states2 [27][8640]
    const float* __restrict__ bias,     // agg_b1 [8640]
    const float* __restrict__ states1,  // [27][320]
    const float* __restrict__ W1,       // up_W1_1 [27][64][640]
    const float* __restrict__ b1,       // [27][64]
    const float* __restrict__ W2,       // up_W2_1 [27][320][64]
    const float* __restrict__ b2,       // [27][320]
    float* __restrict__ agg1,           // ws [8640]
    float* __restrict__ ns1,            // ws [8640]
    int*   __restrict__ cnt)            // ws [27], pre-zeroed
{
    __shared__ float comb[640];
    __shared__ float h[64];
    __shared__ int last;

    const int tid = threadIdx.x;
    const int wv = tid >> 6, lane = tid & 63;
    const int row  = blockIdx.x * 4 + wv;   // 0..8639
    const int node = blockIdx.x / 80;       // 80 blocks/node, rows stay in-node

    const float4* __restrict__ Wr = reinterpret_cast<const float4*>(W + (size_t)row * DOTLEN);
    const float4* __restrict__ xr = reinterpret_cast<const float4*>(x + (size_t)node * DOTLEN);

    float acc = row_dot(Wr, xr, lane);
    acc = wave_reduce_sum(acc);
    if (lane == 0) agg1[row] = acc + bias[row];

    // release our rows, then count completed blocks for this node
    __threadfence();
    __syncthreads();
    if (tid == 0) {
        __threadfence();
        last = atomicAdd(&cnt[node], 1);
    }
    __syncthreads();
    if (last != 79) return;

    // acquire: all 320 agg1 rows of this node are visible
    __threadfence();
    for (int j = tid; j < 320; j += 256) {
        comb[j]       = states1[node * 320 + j];
        comb[320 + j] = agg1[node * 320 + j];
    }
    mlp_core(tid,
             W1 + (size_t)node * 64 * 640, b1 + node * 64,
             W2 + (size_t)node * 320 * 64, b2 + node * 320,
             ns1 + node * 320, comb, h);
}

// Kernel 2: agg0 = agg_W0 . new_states1 + agg_b0 (320 rows, 80 blocks).
// Last block runs the root MLP and writes the final output.
__global__ void __launch_bounds__(256) k2_root(
    const float* __restrict__ W,        // agg_W0 [320][8640]
    const float* __restrict__ ns1,      // ws [8640]
    const float* __restrict__ bias,     // agg_b0 [320]
    const float* __restrict__ ext,      // [320]
    const float* __restrict__ state0,   // [320]
    const float* __restrict__ W1,       // up_W1_0 [64][640]
    const float* __restrict__ b1,       // [64]
    const float* __restrict__ W2,       // up_W2_0 [320][64]
    const float* __restrict__ b2,       // [320]
    float* __restrict__ agg0,           // ws [320]
    float* __restrict__ out,            // d_out [320]
    int*   __restrict__ cnt)            // ws [1], pre-zeroed
{
    __shared__ float comb[640];
    __shared__ float h[64];
    __shared__ int last;

    const int tid = threadIdx.x;
    const int wv = tid >> 6, lane = tid & 63;
    const int row = blockIdx.x * 4 + wv;    // 0..319

    const float4* __restrict__ Wr = reinterpret_cast<const float4*>(W + (size_t)row * DOTLEN);
    const float4* __restrict__ xr = reinterpret_cast<const float4*>(ns1);

    float acc = row_dot(Wr, xr, lane);
    acc = wave_reduce_sum(acc);
    if (lane == 0) agg0[row] = acc + bias[row];

    __threadfence();
    __syncthreads();
    if (tid == 0) {
        __threadfence();
        last = atomicAdd(cnt, 1);
    }
    __syncthreads();
    if (last != 79) return;

    __threadfence();
    for (int j = tid; j < 320; j += 256) {
        comb[j]       = state0[j] + ext[j];
        comb[320 + j] = agg0[j];
    }
    mlp_core(tid, W1, b1, W2, b2, out, comb, h);
}

extern "C" void kernel_launch(void* const* d_in, const int* in_sizes, int n_in,
                              void* d_out, int out_size, void* d_ws, size_t ws_size,
                              hipStream_t stream) {
    const float* ext      = (const float*)d_in[0];
    const float* state0   = (const float*)d_in[1];
    const float* states1  = (const float*)d_in[2];
    const float* states2  = (const float*)d_in[3];
    const float* agg_W0   = (const float*)d_in[4];
    const float* agg_b0   = (const float*)d_in[5];
    const float* agg_W1   = (const float*)d_in[6];
    const float* agg_b1   = (const float*)d_in[7];
    const float* up_W1_0  = (const float*)d_in[8];
    const float* up_b1_0  = (const float*)d_in[9];
    const float* up_W2_0  = (const float*)d_in[10];
    const float* up_b2_0  = (const float*)d_in[11];
    const float* up_W1_1  = (const float*)d_in[12];
    const float* up_b1_1  = (const float*)d_in[13];
    const float* up_W2_1  = (const float*)d_in[14];
    const float* up_b2_1  = (const float*)d_in[15];

    float* out  = (float*)d_out;
    float* ws   = (float*)d_ws;
    float* agg1 = ws;              // 8640 floats
    float* ns1  = ws + 8640;       // 8640 floats
    float* agg0 = ws + 17280;      // 320 floats
    int*   cnt  = (int*)(ws + 17600); // 27 + 1 ints

    // zero the completion counters each replay (graph-capturable memset node)
    hipMemsetAsync(cnt, 0, 28 * sizeof(int), stream);

    k1_agg_mlp<<<2160, 256, 0, stream>>>(agg_W1, states2, agg_b1, states1,
                                         up_W1_1, up_b1_1, up_W2_1, up_b2_1,
                                         agg1, ns1, cnt);
    k2_root<<<80, 256, 0, stream>>>(agg_W0, ns1, agg_b0, ext, state0,
                                    up_W1_0, up_b1_0, up_W2_0, up_b2_0,
                                    agg0, out, cnt + 27);
}

// Round 3
// 232.596 us; speedup vs baseline: 3.2251x; 3.2251x over previous
//
#include <hip/hip_runtime.h>
#include <hip/hip_bf16.h>

// S=64, C=27
// DOTLEN = C*S*5 = 8640 (2160 float4) ; per-node state = S*5 = 320 ; comb = 640 ; hidden = 64
#define DOTLEN 8640

__device__ __forceinline__ float wave_reduce_sum(float v) {
    v += __shfl_xor(v, 32, 64);
    v += __shfl_xor(v, 16, 64);
    v += __shfl_xor(v, 8, 64);
    v += __shfl_xor(v, 4, 64);
    v += __shfl_xor(v, 2, 64);
    v += __shfl_xor(v, 1, 64);
    return v;
}

__device__ __forceinline__ float fma4(float4 w, float4 x, float acc) {
    acc = fmaf(w.x, x.x, acc);
    acc = fmaf(w.y, x.y, acc);
    acc = fmaf(w.z, x.z, acc);
    acc = fmaf(w.w, x.w, acc);
    return acc;
}

// Wave-distributed dot of one 8640-float row against x. 4 independent acc
// chains, 8 loads issued per unrolled step -> high memory-level parallelism.
__device__ __forceinline__ float row_dot(const float4* __restrict__ Wr,
                                         const float4* __restrict__ xr,
                                         int lane) {
    float a0 = 0.f, a1 = 0.f, a2 = 0.f, a3 = 0.f;
    #pragma unroll 2
    for (int base = 0; base < 2048; base += 256) {
        float4 w0 = Wr[base + lane];
        float4 w1 = Wr[base + 64 + lane];
        float4 w2 = Wr[base + 128 + lane];
        float4 w3 = Wr[base + 192 + lane];
        float4 x0 = xr[base + lane];
        float4 x1 = xr[base + 64 + lane];
        float4 x2 = xr[base + 128 + lane];
        float4 x3 = xr[base + 192 + lane];
        a0 = fma4(w0, x0, a0);
        a1 = fma4(w1, x1, a1);
        a2 = fma4(w2, x2, a2);
        a3 = fma4(w3, x3, a3);
    }
    // tail: indices 2048..2159 (112 float4)
    {
        float4 w = Wr[2048 + lane];
        float4 x = xr[2048 + lane];
        a0 = fma4(w, x, a0);
    }
    if (lane < 48) {
        float4 w = Wr[2112 + lane];
        float4 x = xr[2112 + lane];
        a1 = fma4(w, x, a1);
    }
    return (a0 + a1) + (a2 + a3);
}

// Two-layer MLP tail: assumes comb[0:640] staged in LDS (caller), writes
// outp[i] = comb[i] + W2@relu(W1@comb + b1) + b2.  256 threads.
__device__ __forceinline__ void mlp_core(int tid,
                                         const float* __restrict__ W1,
                                         const float* __restrict__ b1,
                                         const float* __restrict__ W2,
                                         const float* __restrict__ b2,
                                         float* __restrict__ outp,
                                         float* comb, float* h) {
    __syncthreads();
    const int wv = tid >> 6, lane = tid & 63;
    for (int k = wv * 16; k < wv * 16 + 16; ++k) {
        float acc = 0.f;
        #pragma unroll
        for (int j = lane; j < 640; j += 64)
            acc = fmaf(W1[k * 640 + j], comb[j], acc);
        acc = wave_reduce_sum(acc);
        if (lane == 0) h[k] = fmaxf(acc + b1[k], 0.f);
    }
    __syncthreads();
    for (int i = tid; i < 320; i += 256) {
        const float4* __restrict__ w = reinterpret_cast<const float4*>(W2 + (size_t)i * 64);
        float acc = 0.f;
        #pragma unroll
        for (int j4 = 0; j4 < 16; ++j4) {
            float4 ww = w[j4];
            acc = fmaf(ww.x, h[4 * j4 + 0], acc);
            acc = fmaf(ww.y, h[4 * j4 + 1], acc);
            acc = fmaf(ww.z, h[4 * j4 + 2], acc);
            acc = fmaf(ww.w, h[4 * j4 + 3], acc);
        }
        outp[i] = comb[i] + acc + b2[i];
    }
}

// Kernel 1: agg1 = agg_W1 . leaf_flat + agg_b1 (8640 rows, 4 rows/block,
// 80 blocks per node). Last block of each node runs that node's update MLP.
// Cross-block visibility via per-word agent-scope atomics (NO fences -> no
// L2 writeback/invalidate storms).
__global__ void __launch_bounds__(256) k1_agg_mlp(
    const float* __restrict__ W,        // agg_W1 [27*320][8640]
    const float* __restrict__ x,        // states2 [27][8640]
    const float* __restrict__ bias,     // agg_b1 [8640]
    const float* __restrict__ states1,  // [27][320]
    const float* __restrict__ W1,       // up_W1_1 [27][64][640]
    const float* __restrict__ b1,       // [27][64]
    const float* __restrict__ W2,       // up_W2_1 [27][320][64]
    const float* __restrict__ b2,       // [27][320]
    float* __restrict__ agg1,           // ws [8640]
    float* __restrict__ ns1,            // ws [8640]
    int*   __restrict__ cnt)            // ws [27], pre-zeroed
{
    __shared__ float comb[640];
    __shared__ float h[64];
    __shared__ int last;

    const int tid = threadIdx.x;
    const int wv = tid >> 6, lane = tid & 63;
    const int row  = blockIdx.x * 4 + wv;   // 0..8639
    const int node = blockIdx.x / 80;       // 80 blocks/node, rows stay in-node

    const float4* __restrict__ Wr = reinterpret_cast<const float4*>(W + (size_t)row * DOTLEN);
    const float4* __restrict__ xr = reinterpret_cast<const float4*>(x + (size_t)node * DOTLEN);

    float acc = row_dot(Wr, xr, lane);
    acc = wave_reduce_sum(acc);
    if (lane == 0) {
        // coherent (cross-XCD visible) store, no cache flush
        __hip_atomic_store(&agg1[row], acc + bias[row],
                           __ATOMIC_RELAXED, __HIP_MEMORY_SCOPE_AGENT);
    }
    __syncthreads();   // drains vmcnt(0) for all waves (barrier semantics)
    if (tid == 0) {
        last = __hip_atomic_fetch_add(&cnt[node], 1,
                                      __ATOMIC_RELAXED, __HIP_MEMORY_SCOPE_AGENT);
    }
    __syncthreads();
    if (last != 79) return;

    // all 320 agg1 rows of this node are at the coherence point; read them
    // with agent-scope loads (bypass potentially-stale caches)
    for (int j = tid; j < 320; j += 256) {
        comb[j]       = states1[node * 320 + j];
        comb[320 + j] = __hip_atomic_load(&agg1[node * 320 + j],
                                          __ATOMIC_RELAXED, __HIP_MEMORY_SCOPE_AGENT);
    }
    mlp_core(tid,
             W1 + (size_t)node * 64 * 640, b1 + node * 64,
             W2 + (size_t)node * 320 * 64, b2 + node * 320,
             ns1 + node * 320, comb, h);
}

// Kernel 2: agg0 = agg_W0 . new_states1 + agg_b0 (320 rows, 80 blocks).
// Last block runs the root MLP and writes the final output.
__global__ void __launch_bounds__(256) k2_root(
    const float* __restrict__ W,        // agg_W0 [320][8640]
    const float* __restrict__ ns1,      // ws [8640] (coherent: kernel boundary)
    const float* __restrict__ bias,     // agg_b0 [320]
    const float* __restrict__ ext,      // [320]
    const float* __restrict__ state0,   // [320]
    const float* __restrict__ W1,       // up_W1_0 [64][640]
    const float* __restrict__ b1,       // [64]
    const float* __restrict__ W2,       // up_W2_0 [320][64]
    const float* __restrict__ b2,       // [320]
    float* __restrict__ agg0,           // ws [320]
    float* __restrict__ out,            // d_out [320]
    int*   __restrict__ cnt)            // ws [1], pre-zeroed
{
    __shared__ float comb[640];
    __shared__ float h[64];
    __shared__ int last;

    const int tid = threadIdx.x;
    const int wv = tid >> 6, lane = tid & 63;
    const int row = blockIdx.x * 4 + wv;    // 0..319

    const float4* __restrict__ Wr = reinterpret_cast<const float4*>(W + (size_t)row * DOTLEN);
    const float4* __restrict__ xr = reinterpret_cast<const float4*>(ns1);

    float acc = row_dot(Wr, xr, lane);
    acc = wave_reduce_sum(acc);
    if (lane == 0) {
        __hip_atomic_store(&agg0[row], acc + bias[row],
                           __ATOMIC_RELAXED, __HIP_MEMORY_SCOPE_AGENT);
    }
    __syncthreads();
    if (tid == 0) {
        last = __hip_atomic_fetch_add(cnt, 1,
                                      __ATOMIC_RELAXED, __HIP_MEMORY_SCOPE_AGENT);
    }
    __syncthreads();
    if (last != 79) return;

    for (int j = tid; j < 320; j += 256) {
        comb[j]       = state0[j] + ext[j];
        comb[320 + j] = __hip_atomic_load(&agg0[j],
                                          __ATOMIC_RELAXED, __HIP_MEMORY_SCOPE_AGENT);
    }
    mlp_core(tid, W1, b1, W2, b2, out, comb, h);
}

extern "C" void kernel_launch(void* const* d_in, const int* in_sizes, int n_in,
                              void* d_out, int out_size, void* d_ws, size_t ws_size,
                              hipStream_t stream) {
    const float* ext      = (const float*)d_in[0];
    const float* state0   = (const float*)d_in[1];
    const float* states1  = (const float*)d_in[2];
    const float* states2  = (const float*)d_in[3];
    const float* agg_W0   = (const float*)d_in[4];
    const float* agg_b0   = (const float*)d_in[5];
    const float* agg_W1   = (const float*)d_in[6];
    const float* agg_b1   = (const float*)d_in[7];
    const float* up_W1_0  = (const float*)d_in[8];
    const float* up_b1_0  = (const float*)d_in[9];
    const float* up_W2_0  = (const float*)d_in[10];
    const float* up_b2_0  = (const float*)d_in[11];
    const float* up_W1_1  = (const float*)d_in[12];
    const float* up_b1_1  = (const float*)d_in[13];
    const float* up_W2_1  = (const float*)d_in[14];
    const float* up_b2_1  = (const float*)d_in[15];

    float* out  = (float*)d_out;
    float* ws   = (float*)d_ws;
    float* agg1 = ws;              // 8640 floats
    float* ns1  = ws + 8640;       // 8640 floats
    float* agg0 = ws + 17280;      // 320 floats
    int*   cnt  = (int*)(ws + 17600); // 27 + 1 ints

    // zero the completion counters each replay (graph-capturable memset node)
    hipMemsetAsync(cnt, 0, 28 * sizeof(int), stream);

    k1_agg_mlp<<<2160, 256, 0, stream>>>(agg_W1, states2, agg_b1, states1,
                                         up_W1_1, up_b1_1, up_W2_1, up_b2_1,
                                         agg1, ns1, cnt);
    k2_root<<<80, 256, 0, stream>>>(agg_W0, ns1, agg_b0, ext, state0,
                                    up_W1_0, up_b1_0, up_W2_0, up_b2_0,
                                    agg0, out, cnt + 27);
}

// Round 4
// 69.111 us; speedup vs baseline: 10.8542x; 3.3656x over previous
//
#include <hip/hip_runtime.h>
#include <hip/hip_bf16.h>

// S=64, C=27
// DOTLEN = 8640 floats = 2160 float4 per row ; state = 320 ; comb = 640 ; hidden = 64

__device__ __forceinline__ float wave_reduce_sum(float v) {
    v += __shfl_xor(v, 32, 64);
    v += __shfl_xor(v, 16, 64);
    v += __shfl_xor(v, 8, 64);
    v += __shfl_xor(v, 4, 64);
    v += __shfl_xor(v, 2, 64);
    v += __shfl_xor(v, 1, 64);
    return v;
}

__device__ __forceinline__ float fma4s(float4 w, float4 x, float acc) {
    acc = fmaf(w.x, x.x, acc);
    acc = fmaf(w.y, x.y, acc);
    acc = fmaf(w.z, x.z, acc);
    acc = fmaf(w.w, x.w, acc);
    return acc;
}

__device__ __forceinline__ float4 add4(float4 a, float4 b) {
    return make_float4(a.x + b.x, a.y + b.y, a.z + b.z, a.w + b.w);
}

// ---------------------------------------------------------------------------
// k1: agg1[8640] = agg_W1 . leaf_flat + agg_b1.
// Column-parallel: block = 4 rows x all 2160 float4 cols; thread t owns cols
// t, t+256, ... Each iteration: 1 x-load + 4 independent W-streams -> high MLP.
// Grid 27 nodes x 80 row-blocks = 2160.
__global__ void __launch_bounds__(256) k1_gemv(
    const float* __restrict__ W,     // [8640][8640] row-major (block-diag use)
    const float* __restrict__ x,     // [27][8640]
    const float* __restrict__ bias,  // [8640]
    float*       __restrict__ y)     // [8640]
{
    const int b    = blockIdx.x;
    const int node = b / 80;
    const int row0 = node * 320 + (b % 80) * 4;
    const int tid  = threadIdx.x;

    const float4* __restrict__ xf  = reinterpret_cast<const float4*>(x) + (size_t)node * 2160;
    const float4* __restrict__ w0p = reinterpret_cast<const float4*>(W) + (size_t)(row0 + 0) * 2160;
    const float4* __restrict__ w1p = reinterpret_cast<const float4*>(W) + (size_t)(row0 + 1) * 2160;
    const float4* __restrict__ w2p = reinterpret_cast<const float4*>(W) + (size_t)(row0 + 2) * 2160;
    const float4* __restrict__ w3p = reinterpret_cast<const float4*>(W) + (size_t)(row0 + 3) * 2160;

    float4 a0 = make_float4(0.f, 0.f, 0.f, 0.f), a1 = a0, a2 = a0, a3 = a0;
    for (int j = tid; j < 2160; j += 256) {
        float4 xv = xf[j];
        float4 w0 = w0p[j];
        float4 w1 = w1p[j];
        float4 w2 = w2p[j];
        float4 w3 = w3p[j];
        a0.x = fmaf(w0.x, xv.x, a0.x); a0.y = fmaf(w0.y, xv.y, a0.y);
        a0.z = fmaf(w0.z, xv.z, a0.z); a0.w = fmaf(w0.w, xv.w, a0.w);
        a1.x = fmaf(w1.x, xv.x, a1.x); a1.y = fmaf(w1.y, xv.y, a1.y);
        a1.z = fmaf(w1.z, xv.z, a1.z); a1.w = fmaf(w1.w, xv.w, a1.w);
        a2.x = fmaf(w2.x, xv.x, a2.x); a2.y = fmaf(w2.y, xv.y, a2.y);
        a2.z = fmaf(w2.z, xv.z, a2.z); a2.w = fmaf(w2.w, xv.w, a2.w);
        a3.x = fmaf(w3.x, xv.x, a3.x); a3.y = fmaf(w3.y, xv.y, a3.y);
        a3.z = fmaf(w3.z, xv.z, a3.z); a3.w = fmaf(w3.w, xv.w, a3.w);
    }
    float s0 = (a0.x + a0.y) + (a0.z + a0.w);
    float s1 = (a1.x + a1.y) + (a1.z + a1.w);
    float s2 = (a2.x + a2.y) + (a2.z + a2.w);
    float s3 = (a3.x + a3.y) + (a3.z + a3.w);
    s0 = wave_reduce_sum(s0);
    s1 = wave_reduce_sum(s1);
    s2 = wave_reduce_sum(s2);
    s3 = wave_reduce_sum(s3);

    __shared__ float red[4][4];
    const int wv = tid >> 6, lane = tid & 63;
    if (lane == 0) { red[wv][0] = s0; red[wv][1] = s1; red[wv][2] = s2; red[wv][3] = s3; }
    __syncthreads();
    if (tid < 4) {
        float v = red[0][tid] + red[1][tid] + red[2][tid] + red[3][tid];
        y[row0 + tid] = v + bias[row0 + tid];
    }
}

// ---------------------------------------------------------------------------
// k2a: h1[27][64] = relu(up_W1_1 @ comb1 + b1), comb1 = [states1[n], agg1[n]].
// Grid 27*16 = 432 blocks; wave computes one (n,k).
__global__ void __launch_bounds__(256) k2a_h(
    const float* __restrict__ states1,  // [27][320]
    const float* __restrict__ agg1,     // [8640] (ws)
    const float* __restrict__ W1,       // [27][64][640]
    const float* __restrict__ b1,       // [27][64]
    float*       __restrict__ h1)       // [27][64] (ws)
{
    __shared__ float comb[640];
    const int nb  = blockIdx.x;
    const int n   = nb / 16;
    const int tid = threadIdx.x;

    float4* combf = reinterpret_cast<float4*>(comb);
    const float4* __restrict__ s1f = reinterpret_cast<const float4*>(states1) + (size_t)n * 80;
    const float4* __restrict__ a1f = reinterpret_cast<const float4*>(agg1) + (size_t)n * 80;
    if (tid < 80)       combf[tid] = s1f[tid];
    else if (tid < 160) combf[tid] = a1f[tid - 80];
    __syncthreads();

    const int wv = tid >> 6, lane = tid & 63;
    const int k  = (nb % 16) * 4 + wv;
    const float4* __restrict__ Wf = reinterpret_cast<const float4*>(W1) + ((size_t)n * 64 + k) * 160;
    float acc = 0.f;
    #pragma unroll
    for (int j = lane; j < 160; j += 64)
        acc = fma4s(Wf[j], combf[j], acc);
    acc = wave_reduce_sum(acc);
    if (lane == 0) h1[n * 64 + k] = fmaxf(acc + b1[n * 64 + k], 0.f);
}

// ---------------------------------------------------------------------------
// k2b: ns1[8640] = states1 + up_W2_1 @ h1 + b2. One wave per output row
// (dot-len 64 == wave width). Grid 2160 blocks.
__global__ void __launch_bounds__(256) k2b_ns(
    const float* __restrict__ states1,  // [8640]
    const float* __restrict__ h1,       // [27][64] (ws)
    const float* __restrict__ W2,       // [8640][64]
    const float* __restrict__ b2,       // [8640]
    float*       __restrict__ ns1)      // [8640] (ws)
{
    const int tid  = threadIdx.x;
    const int wv   = tid >> 6, lane = tid & 63;
    const int i    = blockIdx.x * 4 + wv;   // 0..8639
    const int n    = i / 320;
    float acc = W2[(size_t)i * 64 + lane] * h1[n * 64 + lane];
    acc = wave_reduce_sum(acc);
    if (lane == 0) ns1[i] = states1[i] + acc + b2[i];
}

// ---------------------------------------------------------------------------
// k3: agg0 partials: agg0p[cs][320] = agg_W0[:, slice(cs)] @ ns1[slice(cs)].
// 4 col-slices x 80 row-blocks = 320 blocks, 4 rows/block.
__global__ void __launch_bounds__(256) k3_gemv(
    const float* __restrict__ W,    // [320][8640]
    const float* __restrict__ x,    // ns1 [8640] (ws)
    float*       __restrict__ yp)   // [4][320] partials (ws)
{
    const int b   = blockIdx.x;     // 0..319
    const int cs  = b / 80;         // col slice 0..3
    const int r0  = (b % 80) * 4;
    const int tid = threadIdx.x;

    const float4* __restrict__ xf  = reinterpret_cast<const float4*>(x);
    const float4* __restrict__ w0p = reinterpret_cast<const float4*>(W) + (size_t)(r0 + 0) * 2160;
    const float4* __restrict__ w1p = reinterpret_cast<const float4*>(W) + (size_t)(r0 + 1) * 2160;
    const float4* __restrict__ w2p = reinterpret_cast<const float4*>(W) + (size_t)(r0 + 2) * 2160;
    const float4* __restrict__ w3p = reinterpret_cast<const float4*>(W) + (size_t)(r0 + 3) * 2160;

    float4 a0 = make_float4(0.f, 0.f, 0.f, 0.f), a1 = a0, a2 = a0, a3 = a0;
    const int jend = cs * 540 + 540;
    for (int j = cs * 540 + tid; j < jend; j += 256) {
        float4 xv = xf[j];
        float4 w0 = w0p[j];
        float4 w1 = w1p[j];
        float4 w2 = w2p[j];
        float4 w3 = w3p[j];
        a0.x = fmaf(w0.x, xv.x, a0.x); a0.y = fmaf(w0.y, xv.y, a0.y);
        a0.z = fmaf(w0.z, xv.z, a0.z); a0.w = fmaf(w0.w, xv.w, a0.w);
        a1.x = fmaf(w1.x, xv.x, a1.x); a1.y = fmaf(w1.y, xv.y, a1.y);
        a1.z = fmaf(w1.z, xv.z, a1.z); a1.w = fmaf(w1.w, xv.w, a1.w);
        a2.x = fmaf(w2.x, xv.x, a2.x); a2.y = fmaf(w2.y, xv.y, a2.y);
        a2.z = fmaf(w2.z, xv.z, a2.z); a2.w = fmaf(w2.w, xv.w, a2.w);
        a3.x = fmaf(w3.x, xv.x, a3.x); a3.y = fmaf(w3.y, xv.y, a3.y);
        a3.z = fmaf(w3.z, xv.z, a3.z); a3.w = fmaf(w3.w, xv.w, a3.w);
    }
    float s0 = (a0.x + a0.y) + (a0.z + a0.w);
    float s1 = (a1.x + a1.y) + (a1.z + a1.w);
    float s2 = (a2.x + a2.y) + (a2.z + a2.w);
    float s3 = (a3.x + a3.y) + (a3.z + a3.w);
    s0 = wave_reduce_sum(s0);
    s1 = wave_reduce_sum(s1);
    s2 = wave_reduce_sum(s2);
    s3 = wave_reduce_sum(s3);

    __shared__ float red[4][4];
    const int wv = tid >> 6, lane = tid & 63;
    if (lane == 0) { red[wv][0] = s0; red[wv][1] = s1; red[wv][2] = s2; red[wv][3] = s3; }
    __syncthreads();
    if (tid < 4) {
        yp[cs * 320 + r0 + tid] =
            red[0][tid] + red[1][tid] + red[2][tid] + red[3][tid];
    }
}

// ---------------------------------------------------------------------------
// k4a: h0[64] = relu(up_W1_0 @ comb0 + b1_0), comb0 = [state0+ext, sum(agg0p)+agg_b0].
// Grid 16 blocks; wave computes one k.
__global__ void __launch_bounds__(256) k4a_h(
    const float* __restrict__ state0,  // [320]
    const float* __restrict__ ext,     // [320]
    const float* __restrict__ agg0p,   // [4][320] (ws)
    const float* __restrict__ agg_b0,  // [320]
    const float* __restrict__ W1,      // [64][640]
    const float* __restrict__ b1,      // [64]
    float*       __restrict__ h0)      // [64] (ws)
{
    __shared__ float comb[640];
    const int tid = threadIdx.x;
    float4* combf = reinterpret_cast<float4*>(comb);
    const float4* __restrict__ s0f = reinterpret_cast<const float4*>(state0);
    const float4* __restrict__ exf = reinterpret_cast<const float4*>(ext);
    const float4* __restrict__ p0  = reinterpret_cast<const float4*>(agg0p);
    const float4* __restrict__ p1  = p0 + 80;
    const float4* __restrict__ p2  = p0 + 160;
    const float4* __restrict__ p3  = p0 + 240;
    const float4* __restrict__ b0f = reinterpret_cast<const float4*>(agg_b0);
    if (tid < 80) {
        combf[tid] = add4(s0f[tid], exf[tid]);
    } else if (tid < 160) {
        int jj = tid - 80;
        combf[tid] = add4(add4(add4(p0[jj], p1[jj]), add4(p2[jj], p3[jj])), b0f[jj]);
    }
    __syncthreads();

    const int wv = tid >> 6, lane = tid & 63;
    const int k  = blockIdx.x * 4 + wv;     // 0..63
    const float4* __restrict__ Wf = reinterpret_cast<const float4*>(W1) + (size_t)k * 160;
    float acc = 0.f;
    #pragma unroll
    for (int j = lane; j < 160; j += 64)
        acc = fma4s(Wf[j], combf[j], acc);
    acc = wave_reduce_sum(acc);
    if (lane == 0) h0[k] = fmaxf(acc + b1[k], 0.f);
}

// ---------------------------------------------------------------------------
// k4b: out[320] = (state0+ext) + up_W2_0 @ h0 + b2_0. One wave per row.
__global__ void __launch_bounds__(256) k4b_out(
    const float* __restrict__ state0,  // [320]
    const float* __restrict__ ext,     // [320]
    const float* __restrict__ h0,      // [64] (ws)
    const float* __restrict__ W2,      // [320][64]
    const float* __restrict__ b2,      // [320]
    float*       __restrict__ out)     // [320]
{
    const int tid  = threadIdx.x;
    const int wv   = tid >> 6, lane = tid & 63;
    const int i    = blockIdx.x * 4 + wv;   // 0..319
    float acc = W2[(size_t)i * 64 + lane] * h0[lane];
    acc = wave_reduce_sum(acc);
    if (lane == 0) out[i] = state0[i] + ext[i] + acc + b2[i];
}

extern "C" void kernel_launch(void* const* d_in, const int* in_sizes, int n_in,
                              void* d_out, int out_size, void* d_ws, size_t ws_size,
                              hipStream_t stream) {
    const float* ext      = (const float*)d_in[0];
    const float* state0   = (const float*)d_in[1];
    const float* states1  = (const float*)d_in[2];
    const float* states2  = (const float*)d_in[3];
    const float* agg_W0   = (const float*)d_in[4];
    const float* agg_b0   = (const float*)d_in[5];
    const float* agg_W1   = (const float*)d_in[6];
    const float* agg_b1   = (const float*)d_in[7];
    const float* up_W1_0  = (const float*)d_in[8];
    const float* up_b1_0  = (const float*)d_in[9];
    const float* up_W2_0  = (const float*)d_in[10];
    const float* up_b2_0  = (const float*)d_in[11];
    const float* up_W1_1  = (const float*)d_in[12];
    const float* up_b1_1  = (const float*)d_in[13];
    const float* up_W2_1  = (const float*)d_in[14];
    const float* up_b2_1  = (const float*)d_in[15];

    float* out   = (float*)d_out;
    float* ws    = (float*)d_ws;
    float* agg1  = ws;             // 8640
    float* h1    = ws + 8640;      // 1728
    float* ns1   = ws + 10368;     // 8640
    float* agg0p = ws + 19008;     // 1280
    float* h0    = ws + 20288;     // 64

    k1_gemv<<<2160, 256, 0, stream>>>(agg_W1, states2, agg_b1, agg1);
    k2a_h  <<<432,  256, 0, stream>>>(states1, agg1, up_W1_1, up_b1_1, h1);
    k2b_ns <<<2160, 256, 0, stream>>>(states1, h1, up_W2_1, up_b2_1, ns1);
    k3_gemv<<<320,  256, 0, stream>>>(agg_W0, ns1, agg0p);
    k4a_h  <<<16,   256, 0, stream>>>(state0, ext, agg0p, agg_b0, up_W1_0, up_b1_0, h0);
    k4b_out<<<80,   256, 0, stream>>>(state0, ext, h0, up_W2_0, up_b2_0, out);
}